// Round 2
// baseline (107144.177 us; speedup 1.0000x reference)
//
#include <hip/hip_runtime.h>
#include <hip/hip_cooperative_groups.h>

namespace cg = cooperative_groups;

#define T_SEQ 4096
#define D_IN  512
#define D_H   2048
#define D_C   2560
#define D_OUT 512
#define NBLK  256
#define NTHR  512

__device__ __forceinline__ void dot4(float& acc, const float4& a, const float4& b) {
    acc = fmaf(a.x, b.x, acc);
    acc = fmaf(a.y, b.y, acc);
    acc = fmaf(a.z, b.z, acc);
    acc = fmaf(a.w, b.w, acc);
}

__global__ __launch_bounds__(NTHR, 2) void lstm_persist(
    const float* __restrict__ x,         // [T_SEQ, D_IN]
    const float* __restrict__ hidden_in, // [D_H] (passthrough output)
    const float* __restrict__ Wi, const float* __restrict__ bi,
    const float* __restrict__ Wg, const float* __restrict__ bg,
    const float* __restrict__ Wo, const float* __restrict__ bo,
    const float* __restrict__ Wout, const float* __restrict__ bout,
    float* __restrict__ out,             // [D_OUT + D_H]
    float* __restrict__ hbuf)            // [2][D_H] in d_ws
{
    cg::grid_group grid = cg::this_grid();
    const int tid  = threadIdx.x;
    const int lane = tid & 63;
    const int wv   = tid >> 6;                 // wave in block, 0..7
    const int j    = blockIdx.x * 8 + wv;      // hidden unit 0..2047
    const int kbase = lane * 4;                // lane's 4-elem slice base

    __shared__ float lds_h[D_H];

    // ---- load this wave's 3 gate weight rows into registers (stay for all steps)
    float4 wiv[10], wgv[10], wov[10];
    {
        const float* pi = Wi + (size_t)j * D_C + kbase;
        const float* pg = Wg + (size_t)j * D_C + kbase;
        const float* po = Wo + (size_t)j * D_C + kbase;
#pragma unroll
        for (int r = 0; r < 10; ++r) {
            wiv[r] = *reinterpret_cast<const float4*>(pi + 256 * r);
            wgv[r] = *reinterpret_cast<const float4*>(pg + 256 * r);
            wov[r] = *reinterpret_cast<const float4*>(po + 256 * r);
        }
    }
    const float sbi = bi[j];
    const float sbg = bg[j];
    const float sbo = bo[j];

    // ---- h0 = 0 (d_ws is poisoned 0xAA each call; must init ourselves)
    if (lane == 0) {
        __hip_atomic_store(&hbuf[j], 0.0f, __ATOMIC_RELAXED, __HIP_MEMORY_SCOPE_AGENT);
    }
    grid.sync();

#pragma unroll 1
    for (int t = 0; t < T_SEQ; ++t) {
        const float* hc = hbuf + (t & 1) * D_H;        // read buffer
        float*       hn = hbuf + ((t + 1) & 1) * D_H;  // write buffer

        // stage h into LDS: 512 threads x 4 coherent dword loads (agent scope
        // -> bypasses non-coherent L1/L2, served from Infinity Cache)
        float a0 = __hip_atomic_load(hc + 4 * tid + 0, __ATOMIC_RELAXED, __HIP_MEMORY_SCOPE_AGENT);
        float a1 = __hip_atomic_load(hc + 4 * tid + 1, __ATOMIC_RELAXED, __HIP_MEMORY_SCOPE_AGENT);
        float a2 = __hip_atomic_load(hc + 4 * tid + 2, __ATOMIC_RELAXED, __HIP_MEMORY_SCOPE_AGENT);
        float a3 = __hip_atomic_load(hc + 4 * tid + 3, __ATOMIC_RELAXED, __HIP_MEMORY_SCOPE_AGENT);

        // x_t slice for this lane (plain cached loads; x is read-only)
        const float* xt = x + (size_t)t * D_IN;
        const float4 xv0 = *reinterpret_cast<const float4*>(xt + kbase);
        const float4 xv1 = *reinterpret_cast<const float4*>(xt + kbase + 256);

        *reinterpret_cast<float4*>(&lds_h[4 * tid]) = make_float4(a0, a1, a2, a3);
        __syncthreads();

        float ai = 0.f, ag = 0.f, ao = 0.f;
        // comb[k] for k < 512 comes from x_t
        dot4(ai, wiv[0], xv0); dot4(ai, wiv[1], xv1);
        dot4(ag, wgv[0], xv0); dot4(ag, wgv[1], xv1);
        dot4(ao, wov[0], xv0); dot4(ao, wov[1], xv1);
        // comb[k] for k >= 512 comes from h_{t-1} (LDS)
#pragma unroll
        for (int r = 2; r < 10; ++r) {
            const float4 hv = *reinterpret_cast<const float4*>(&lds_h[kbase + 256 * (r - 2)]);
            dot4(ai, wiv[r], hv);
            dot4(ag, wgv[r], hv);
            dot4(ao, wov[r], hv);
        }

        // 64-lane butterfly reduce of the 3 partial dots
#pragma unroll
        for (int off = 32; off; off >>= 1) {
            ai += __shfl_xor(ai, off, 64);
            ag += __shfl_xor(ag, off, 64);
            ao += __shfl_xor(ao, off, 64);
        }

        if (lane == 0) {
            const float zi = ai + sbi;
            const float zg = ag + sbg;
            const float zo = ao + sbo;
            const float it = 1.0f / (1.0f + __expf(-zi));
            const float e2g = __expf(-2.0f * zg);
            const float gt = (1.0f - e2g) / (1.0f + e2g);
            const float ot = 1.0f / (1.0f + __expf(-zo));
            const float c  = it * gt;
            const float e2c = __expf(-2.0f * c);
            const float th = (1.0f - e2c) / (1.0f + e2c);
            __hip_atomic_store(&hn[j], ot * th, __ATOMIC_RELAXED, __HIP_MEMORY_SCOPE_AGENT);
        }

        // one barrier per step: also protects LDS reuse (grid.sync >= block sync)
        grid.sync();
    }

    // ---- epilogue. final h is hbuf[0] (T_SEQ even). last grid.sync done above.
    if (blockIdx.x < 64) {
        // out[ow] = dot(h_final, Wout[ow,:]) + bout[ow], ow = 0..511
        float b0 = __hip_atomic_load(hbuf + 4 * tid + 0, __ATOMIC_RELAXED, __HIP_MEMORY_SCOPE_AGENT);
        float b1 = __hip_atomic_load(hbuf + 4 * tid + 1, __ATOMIC_RELAXED, __HIP_MEMORY_SCOPE_AGENT);
        float b2 = __hip_atomic_load(hbuf + 4 * tid + 2, __ATOMIC_RELAXED, __HIP_MEMORY_SCOPE_AGENT);
        float b3 = __hip_atomic_load(hbuf + 4 * tid + 3, __ATOMIC_RELAXED, __HIP_MEMORY_SCOPE_AGENT);
        *reinterpret_cast<float4*>(&lds_h[4 * tid]) = make_float4(b0, b1, b2, b3);
        __syncthreads();

        const int ow = blockIdx.x * 8 + wv;
        const float* pw = Wout + (size_t)ow * D_H + kbase;
        float acc = 0.f;
#pragma unroll
        for (int r = 0; r < 8; ++r) {
            const float4 w4 = *reinterpret_cast<const float4*>(pw + 256 * r);
            const float4 hv = *reinterpret_cast<const float4*>(&lds_h[kbase + 256 * r]);
            dot4(acc, w4, hv);
        }
#pragma unroll
        for (int off = 32; off; off >>= 1) acc += __shfl_xor(acc, off, 64);
        if (lane == 0) out[ow] = acc + bout[ow];
    } else if (blockIdx.x >= 64 && blockIdx.x < 68) {
        // passthrough: out[512 .. 2559] = hidden_in[0 .. 2047]
        const int idx = (blockIdx.x - 64) * NTHR + tid;
        out[D_OUT + idx] = hidden_in[idx];
    }
}

extern "C" void kernel_launch(void* const* d_in, const int* in_sizes, int n_in,
                              void* d_out, int out_size, void* d_ws, size_t ws_size,
                              hipStream_t stream) {
    const float* x      = (const float*)d_in[0];
    const float* hidden = (const float*)d_in[1];
    const float* Wi     = (const float*)d_in[2];
    const float* bi     = (const float*)d_in[3];
    const float* Wg     = (const float*)d_in[4];
    const float* bg     = (const float*)d_in[5];
    const float* Wo     = (const float*)d_in[6];
    const float* bo     = (const float*)d_in[7];
    const float* Wout   = (const float*)d_in[8];
    const float* bout   = (const float*)d_in[9];
    float* out  = (float*)d_out;
    float* hbuf = (float*)d_ws;   // 2 * 2048 * 4B = 16 KB

    void* args[] = {(void*)&x, (void*)&hidden, (void*)&Wi, (void*)&bi,
                    (void*)&Wg, (void*)&bg, (void*)&Wo, (void*)&bo,
                    (void*)&Wout, (void*)&bout, (void*)&out, (void*)&hbuf};
    (void)hipLaunchCooperativeKernel((const void*)lstm_persist,
                                     dim3(NBLK), dim3(NTHR), args, 0, stream);
}

// Round 3
// 45465.033 us; speedup vs baseline: 2.3566x; 2.3566x over previous
//
#include <hip/hip_runtime.h>
#include <hip/hip_cooperative_groups.h>

namespace cg = cooperative_groups;

#define T_SEQ 4096
#define D_IN  512
#define D_H   2048
#define D_C   2560
#define D_OUT 512
#define NBLK  256
#define NTHR  512

__device__ __forceinline__ void dot4(float& acc, const float4& a, const float4& b) {
    acc = fmaf(a.x, b.x, acc);
    acc = fmaf(a.y, b.y, acc);
    acc = fmaf(a.z, b.z, acc);
    acc = fmaf(a.w, b.w, acc);
}

// Lightweight grid barrier: monotonic counter, agent scope, NO cache
// invalidation (unlike cg::grid.sync whose system-scope fences blow away
// L1/L2 every step). Release = fetch_add, acquire = spin load.
__device__ __forceinline__ void gbar(unsigned* cnt, unsigned target) {
    __syncthreads();                     // all block's h-stores issued & drained
    if (threadIdx.x == 0) {
        __hip_atomic_fetch_add(cnt, 1u, __ATOMIC_ACQ_REL, __HIP_MEMORY_SCOPE_AGENT);
        while (__hip_atomic_load(cnt, __ATOMIC_ACQUIRE, __HIP_MEMORY_SCOPE_AGENT) < target) {
            __builtin_amdgcn_s_sleep(2);
        }
    }
    __syncthreads();
}

__global__ __launch_bounds__(NTHR, 2) void lstm_persist(
    const float* __restrict__ x,         // [T_SEQ, D_IN]
    const float* __restrict__ hidden_in, // [D_H] (passthrough output)
    const float* __restrict__ Wi, const float* __restrict__ bi,
    const float* __restrict__ Wg, const float* __restrict__ bg,
    const float* __restrict__ Wo, const float* __restrict__ bo,
    const float* __restrict__ Wout, const float* __restrict__ bout,
    float* __restrict__ out,             // [D_OUT + D_H]
    float* __restrict__ hbuf)            // d_ws: [2][D_H] floats + 1 counter
{
    cg::grid_group grid = cg::this_grid();
    const int tid  = threadIdx.x;
    const int lane = tid & 63;
    const int wv   = tid >> 6;                 // wave in block, 0..7
    const int j    = blockIdx.x * 8 + wv;      // hidden unit 0..2047
    const int kbase = lane * 4;                // lane's 4-elem slice base

    unsigned* cnt = (unsigned*)(hbuf + 2 * D_H);

    __shared__ float lds_h[D_H];

    // ---- load this wave's 3 gate weight rows (ideally register-resident;
    // even if the compiler re-loads, L1/L2 now stay warm across steps)
    float4 wiv[10], wgv[10], wov[10];
    {
        const float* pi = Wi + (size_t)j * D_C + kbase;
        const float* pg = Wg + (size_t)j * D_C + kbase;
        const float* po = Wo + (size_t)j * D_C + kbase;
#pragma unroll
        for (int r = 0; r < 10; ++r) {
            wiv[r] = *reinterpret_cast<const float4*>(pi + 256 * r);
            wgv[r] = *reinterpret_cast<const float4*>(pg + 256 * r);
            wov[r] = *reinterpret_cast<const float4*>(po + 256 * r);
        }
    }
    const float sbi = bi[j];
    const float sbg = bg[j];
    const float sbo = bo[j];

    // ---- init: h0 = 0, barrier counter = 0 (d_ws poisoned 0xAA each call)
    if (lane == 0) {
        __hip_atomic_store(&hbuf[j], 0.0f, __ATOMIC_RELAXED, __HIP_MEMORY_SCOPE_AGENT);
    }
    if (blockIdx.x == 0 && tid == 0) {
        __hip_atomic_store(cnt, 0u, __ATOMIC_RELAXED, __HIP_MEMORY_SCOPE_AGENT);
    }
    grid.sync();   // the ONLY cg sync — publishes init to all XCDs

    // software-pipelined x loads
    float4 xv0 = *reinterpret_cast<const float4*>(x + kbase);
    float4 xv1 = *reinterpret_cast<const float4*>(x + kbase + 256);

#pragma unroll 1
    for (int t = 0; t < T_SEQ; ++t) {
        const float* hc = hbuf + (t & 1) * D_H;        // read buffer
        float*       hn = hbuf + ((t + 1) & 1) * D_H;  // write buffer

        // stage h into LDS: agent-scope atomic loads bypass stale L1/L2
        float a0 = __hip_atomic_load(hc + 4 * tid + 0, __ATOMIC_RELAXED, __HIP_MEMORY_SCOPE_AGENT);
        float a1 = __hip_atomic_load(hc + 4 * tid + 1, __ATOMIC_RELAXED, __HIP_MEMORY_SCOPE_AGENT);
        float a2 = __hip_atomic_load(hc + 4 * tid + 2, __ATOMIC_RELAXED, __HIP_MEMORY_SCOPE_AGENT);
        float a3 = __hip_atomic_load(hc + 4 * tid + 3, __ATOMIC_RELAXED, __HIP_MEMORY_SCOPE_AGENT);
        *reinterpret_cast<float4*>(&lds_h[4 * tid]) = make_float4(a0, a1, a2, a3);
        __syncthreads();

        float ai = 0.f, ag = 0.f, ao = 0.f;
        // x part (k < 512)
        dot4(ai, wiv[0], xv0); dot4(ai, wiv[1], xv1);
        dot4(ag, wgv[0], xv0); dot4(ag, wgv[1], xv1);
        dot4(ao, wov[0], xv0); dot4(ao, wov[1], xv1);
        // h part (k >= 512), from LDS
#pragma unroll
        for (int r = 2; r < 10; ++r) {
            const float4 hv = *reinterpret_cast<const float4*>(&lds_h[kbase + 256 * (r - 2)]);
            dot4(ai, wiv[r], hv);
            dot4(ag, wgv[r], hv);
            dot4(ao, wov[r], hv);
        }

        // 64-lane butterfly reduce
#pragma unroll
        for (int off = 32; off; off >>= 1) {
            ai += __shfl_xor(ai, off, 64);
            ag += __shfl_xor(ag, off, 64);
            ao += __shfl_xor(ao, off, 64);
        }

        if (lane == 0) {
            const float zi = ai + sbi;
            const float zg = ag + sbg;
            const float zo = ao + sbo;
            const float it = 1.0f / (1.0f + __expf(-zi));
            const float e2g = __expf(-2.0f * zg);
            const float gt = (1.0f - e2g) / (1.0f + e2g);
            const float ot = 1.0f / (1.0f + __expf(-zo));
            const float c  = it * gt;
            const float e2c = __expf(-2.0f * c);
            const float th = (1.0f - e2c) / (1.0f + e2c);
            __hip_atomic_store(&hn[j], ot * th, __ATOMIC_RELAXED, __HIP_MEMORY_SCOPE_AGENT);
        }

        // prefetch next x slice while stores drain
        const int tn = (t + 1 < T_SEQ) ? t + 1 : t;
        const float* xt = x + (size_t)tn * D_IN;
        xv0 = *reinterpret_cast<const float4*>(xt + kbase);
        xv1 = *reinterpret_cast<const float4*>(xt + kbase + 256);

        gbar(cnt, (unsigned)NBLK * (unsigned)(t + 1));
    }

    // ---- epilogue. final h is hbuf[0] (T_SEQ even); last gbar made it visible.
    if (blockIdx.x < 64) {
        float b0 = __hip_atomic_load(hbuf + 4 * tid + 0, __ATOMIC_RELAXED, __HIP_MEMORY_SCOPE_AGENT);
        float b1 = __hip_atomic_load(hbuf + 4 * tid + 1, __ATOMIC_RELAXED, __HIP_MEMORY_SCOPE_AGENT);
        float b2 = __hip_atomic_load(hbuf + 4 * tid + 2, __ATOMIC_RELAXED, __HIP_MEMORY_SCOPE_AGENT);
        float b3 = __hip_atomic_load(hbuf + 4 * tid + 3, __ATOMIC_RELAXED, __HIP_MEMORY_SCOPE_AGENT);
        *reinterpret_cast<float4*>(&lds_h[4 * tid]) = make_float4(b0, b1, b2, b3);
        __syncthreads();

        const int ow = blockIdx.x * 8 + wv;
        const float* pw = Wout + (size_t)ow * D_H + kbase;
        float acc = 0.f;
#pragma unroll
        for (int r = 0; r < 8; ++r) {
            const float4 w4 = *reinterpret_cast<const float4*>(pw + 256 * r);
            const float4 hv = *reinterpret_cast<const float4*>(&lds_h[kbase + 256 * r]);
            dot4(acc, w4, hv);
        }
#pragma unroll
        for (int off = 32; off; off >>= 1) acc += __shfl_xor(acc, off, 64);
        if (lane == 0) out[ow] = acc + bout[ow];
    } else if (blockIdx.x >= 64 && blockIdx.x < 68) {
        // passthrough: out[512 .. 2559] = hidden_in[0 .. 2047]
        const int idx = (blockIdx.x - 64) * NTHR + tid;
        out[D_OUT + idx] = hidden_in[idx];
    }
}

extern "C" void kernel_launch(void* const* d_in, const int* in_sizes, int n_in,
                              void* d_out, int out_size, void* d_ws, size_t ws_size,
                              hipStream_t stream) {
    const float* x      = (const float*)d_in[0];
    const float* hidden = (const float*)d_in[1];
    const float* Wi     = (const float*)d_in[2];
    const float* bi     = (const float*)d_in[3];
    const float* Wg     = (const float*)d_in[4];
    const float* bg     = (const float*)d_in[5];
    const float* Wo     = (const float*)d_in[6];
    const float* bo     = (const float*)d_in[7];
    const float* Wout   = (const float*)d_in[8];
    const float* bout   = (const float*)d_in[9];
    float* out  = (float*)d_out;
    float* hbuf = (float*)d_ws;   // 2*2048 floats (16 KB) + barrier counter

    void* args[] = {(void*)&x, (void*)&hidden, (void*)&Wi, (void*)&bi,
                    (void*)&Wg, (void*)&bg, (void*)&Wo, (void*)&bo,
                    (void*)&Wout, (void*)&bout, (void*)&out, (void*)&hbuf};
    (void)hipLaunchCooperativeKernel((const void*)lstm_persist,
                                     dim3(NBLK), dim3(NTHR), args, 0, stream);
}

// Round 4
// 13821.330 us; speedup vs baseline: 7.7521x; 3.2895x over previous
//
#include <hip/hip_runtime.h>
#include <hip/hip_cooperative_groups.h>

namespace cg = cooperative_groups;

#define T_SEQ 4096
#define D_IN  512
#define D_H   2048
#define D_C   2560
#define D_OUT 512
#define NBLK  256
#define NTHR  1024
#define UPB   8     // hidden units per block (16 waves = 2 waves/unit)

__device__ __forceinline__ void dot4(float& acc, const float4& a, const float4& b) {
    acc = fmaf(a.x, b.x, acc);
    acc = fmaf(a.y, b.y, acc);
    acc = fmaf(a.z, b.z, acc);
    acc = fmaf(a.w, b.w, acc);
}

__device__ __forceinline__ float agload(const float* p) {
    return __hip_atomic_load(p, __ATOMIC_RELAXED, __HIP_MEMORY_SCOPE_AGENT);
}
__device__ __forceinline__ void agstore(float* p, float v) {
    __hip_atomic_store(p, v, __ATOMIC_RELAXED, __HIP_MEMORY_SCOPE_AGENT);
}

// All cross-block data (hbuf, flags) moves ONLY through relaxed agent-scope
// atomics: they bypass the non-coherent L1/L2 to the coherence point, so no
// acquire (= buffer_inv, an L2-wide invalidation!) is ever needed. Release
// ordering store(h) -> store(flag) is a raw s_waitcnt vmcnt(0).

__global__ __launch_bounds__(NTHR, 4) void lstm_persist(
    const float* __restrict__ x,         // [T_SEQ, D_IN]
    const float* __restrict__ hidden_in, // [D_H] (passthrough output)
    const float* __restrict__ Wi, const float* __restrict__ bi,
    const float* __restrict__ Wg, const float* __restrict__ bg,
    const float* __restrict__ Wo, const float* __restrict__ bo,
    const float* __restrict__ Wout, const float* __restrict__ bout,
    float* __restrict__ out,             // [D_OUT + D_H]
    float* __restrict__ ws)              // d_ws: [2][D_H] h + [NBLK] flags
{
    cg::grid_group grid = cg::this_grid();
    const int tid  = threadIdx.x;
    const int lane = tid & 63;
    const int w    = tid >> 6;      // wave 0..15
    const int u    = w >> 1;        // unit-local 0..7
    const int hh   = w & 1;         // half of the 2560-dot: 0 -> [0,1280), 1 -> [1280,2560)
    const int j    = blockIdx.x * UPB + u;   // hidden unit 0..2047
    const int kb   = lane * 4;

    float*    hbuf  = ws;                         // 2 * 2048 floats
    unsigned* flags = (unsigned*)(ws + 2 * D_H);  // 256 monotonic step flags

    __shared__ float lds_h[D_H];
    __shared__ float part[16][3];

    // ---- init shared state (ws poisoned 0xAA every call)
    if (blockIdx.x == 0) {
        for (int i = tid; i < 2 * D_H; i += NTHR) agstore(&hbuf[i], 0.0f);
        if (tid < NBLK)
            __hip_atomic_store(&flags[tid], 0u, __ATOMIC_RELAXED, __HIP_MEMORY_SCOPE_AGENT);
    }
    grid.sync();   // the only cg sync; publishes init before anything is cached

    // ---- this wave's half-rows of Wi/Wg/Wo: 15 float4 = 60 VGPRs, pinned
    float4 wiv[5], wgv[5], wov[5];
    {
        const size_t ro = (size_t)j * D_C + hh * 1280 + kb;
        const float* pi = Wi + ro;
        const float* pg = Wg + ro;
        const float* po = Wo + ro;
#pragma unroll
        for (int r = 0; r < 5; ++r) {
            wiv[r] = *reinterpret_cast<const float4*>(pi + 256 * r);
            wgv[r] = *reinterpret_cast<const float4*>(pg + 256 * r);
            wov[r] = *reinterpret_cast<const float4*>(po + 256 * r);
        }
    }
    // keep-alive: make the loaded values opaque so the compiler cannot
    // rematerialize the loads inside the t-loop (R3 showed VGPR=80 => reloads)
#pragma unroll
    for (int r = 0; r < 5; ++r) {
        asm volatile("" : "+v"(wiv[r].x), "+v"(wiv[r].y), "+v"(wiv[r].z), "+v"(wiv[r].w));
        asm volatile("" : "+v"(wgv[r].x), "+v"(wgv[r].y), "+v"(wgv[r].z), "+v"(wgv[r].w));
        asm volatile("" : "+v"(wov[r].x), "+v"(wov[r].y), "+v"(wov[r].z), "+v"(wov[r].w));
    }

    // biases for the 8 units, held by lanes 0..7 of wave 0
    float sbi = 0.f, sbg = 0.f, sbo = 0.f;
    if (tid < UPB) {
        sbi = bi[blockIdx.x * UPB + tid];
        sbg = bg[blockIdx.x * UPB + tid];
        sbo = bo[blockIdx.x * UPB + tid];
    }

#pragma unroll 1
    for (int t = 0; t < T_SEQ; ++t) {
        // x_t slice (independent of flags -> issue before the poll)
        float4 xv0, xv1;
        if (hh == 0) {
            const float* xt = x + (size_t)t * D_IN;
            xv0 = *reinterpret_cast<const float4*>(xt + kb);
            xv1 = *reinterpret_cast<const float4*>(xt + kb + 256);
        }

        // ---- barrier arrival check: wave 0 polls all 256 flags (relaxed!)
        if (w == 0) {
            const unsigned tgt = (unsigned)t;
            for (;;) {
                bool ok = true;
#pragma unroll
                for (int r = 0; r < 4; ++r)
                    ok &= (__hip_atomic_load(&flags[lane * 4 + r], __ATOMIC_RELAXED,
                                             __HIP_MEMORY_SCOPE_AGENT) >= tgt);
                if (__all(ok)) break;
                __builtin_amdgcn_s_sleep(1);
            }
        }
        __syncthreads();   // releases block; also orders prior-iter LDS reads

        // ---- stage h_t into LDS (coalesced, cache-bypassing loads)
        const float* hc = hbuf + (t & 1) * D_H;
        if (tid < 512) {
            float v0 = agload(hc + tid);
            float v1 = agload(hc + tid + 512);
            float v2 = agload(hc + tid + 1024);
            float v3 = agload(hc + tid + 1536);
            lds_h[tid]        = v0;
            lds_h[tid + 512]  = v1;
            lds_h[tid + 1024] = v2;
            lds_h[tid + 1536] = v3;
        }
        __syncthreads();

        // ---- 3 gate dots over this wave's 1280-wide half
        float ai = 0.f, ag = 0.f, ao = 0.f;
        if (hh == 0) {
            dot4(ai, wiv[0], xv0); dot4(ai, wiv[1], xv1);
            dot4(ag, wgv[0], xv0); dot4(ag, wgv[1], xv1);
            dot4(ao, wov[0], xv0); dot4(ao, wov[1], xv1);
#pragma unroll
            for (int r = 2; r < 5; ++r) {
                const float4 hv = *reinterpret_cast<const float4*>(&lds_h[(r - 2) * 256 + kb]);
                dot4(ai, wiv[r], hv);
                dot4(ag, wgv[r], hv);
                dot4(ao, wov[r], hv);
            }
        } else {
#pragma unroll
            for (int r = 0; r < 5; ++r) {
                const float4 hv = *reinterpret_cast<const float4*>(&lds_h[768 + r * 256 + kb]);
                dot4(ai, wiv[r], hv);
                dot4(ag, wgv[r], hv);
                dot4(ao, wov[r], hv);
            }
        }

#pragma unroll
        for (int off = 32; off; off >>= 1) {
            ai += __shfl_xor(ai, off, 64);
            ag += __shfl_xor(ag, off, 64);
            ao += __shfl_xor(ao, off, 64);
        }
        if (lane == 0) { part[w][0] = ai; part[w][1] = ag; part[w][2] = ao; }
        __syncthreads();

        // ---- combine halves + activations + publish h (wave 0, lanes 0..7)
        if (tid < UPB) {
            const float zi = part[2 * tid][0] + part[2 * tid + 1][0] + sbi;
            const float zg = part[2 * tid][1] + part[2 * tid + 1][1] + sbg;
            const float zo = part[2 * tid][2] + part[2 * tid + 1][2] + sbo;
            const float it = 1.0f / (1.0f + __expf(-zi));
            const float e2g = __expf(-2.0f * zg);
            const float gt = (1.0f - e2g) / (1.0f + e2g);
            const float ot = 1.0f / (1.0f + __expf(-zo));
            const float c  = it * gt;
            const float e2c = __expf(-2.0f * c);
            const float th = (1.0f - e2c) / (1.0f + e2c);
            agstore(&hbuf[((t + 1) & 1) * D_H + blockIdx.x * UPB + tid], ot * th);
        }
        if (w == 0) {
            // release: drain wave 0's h stores to the coherence point, then flag
            asm volatile("s_waitcnt vmcnt(0)" ::: "memory");
            if (lane == 0)
                __hip_atomic_store(&flags[blockIdx.x], (unsigned)(t + 1),
                                   __ATOMIC_RELAXED, __HIP_MEMORY_SCOPE_AGENT);
        }
    }

    // ---- epilogue: out = Wout @ h_final + bout ; passthrough hidden_in
    if (blockIdx.x < 64) {
        if (w == 0) {                      // wait for ALL blocks' final h
            for (;;) {
                bool ok = true;
#pragma unroll
                for (int r = 0; r < 4; ++r)
                    ok &= (__hip_atomic_load(&flags[lane * 4 + r], __ATOMIC_RELAXED,
                                             __HIP_MEMORY_SCOPE_AGENT) >= (unsigned)T_SEQ);
                if (__all(ok)) break;
                __builtin_amdgcn_s_sleep(1);
            }
        }
        __syncthreads();
        if (tid < 512) {                   // final h lives in hbuf[0] (T_SEQ even)
            lds_h[tid]        = agload(hbuf + tid);
            lds_h[tid + 512]  = agload(hbuf + tid + 512);
            lds_h[tid + 1024] = agload(hbuf + tid + 1024);
            lds_h[tid + 1536] = agload(hbuf + tid + 1536);
        }
        __syncthreads();
        if (w < 8) {
            const int ow = blockIdx.x * 8 + w;
            const float* pw = Wout + (size_t)ow * D_H + kb;
            float acc = 0.f;
#pragma unroll
            for (int r = 0; r < 8; ++r) {
                const float4 w4 = *reinterpret_cast<const float4*>(pw + 256 * r);
                const float4 hv = *reinterpret_cast<const float4*>(&lds_h[kb + 256 * r]);
                dot4(acc, w4, hv);
            }
#pragma unroll
            for (int off = 32; off; off >>= 1) acc += __shfl_xor(acc, off, 64);
            if (lane == 0) out[ow] = acc + bout[ow];
        }
    } else if (blockIdx.x >= 64 && blockIdx.x < 66) {
        const int idx = (blockIdx.x - 64) * NTHR + tid;   // 2048 floats
        out[D_OUT + idx] = hidden_in[idx];
    }
}

extern "C" void kernel_launch(void* const* d_in, const int* in_sizes, int n_in,
                              void* d_out, int out_size, void* d_ws, size_t ws_size,
                              hipStream_t stream) {
    const float* x      = (const float*)d_in[0];
    const float* hidden = (const float*)d_in[1];
    const float* Wi     = (const float*)d_in[2];
    const float* bi     = (const float*)d_in[3];
    const float* Wg     = (const float*)d_in[4];
    const float* bg     = (const float*)d_in[5];
    const float* Wo     = (const float*)d_in[6];
    const float* bo     = (const float*)d_in[7];
    const float* Wout   = (const float*)d_in[8];
    const float* bout   = (const float*)d_in[9];
    float* out = (float*)d_out;
    float* ws  = (float*)d_ws;   // 16 KB h double-buffer + 1 KB flags

    void* args[] = {(void*)&x, (void*)&hidden, (void*)&Wi, (void*)&bi,
                    (void*)&Wg, (void*)&bg, (void*)&Wo, (void*)&bo,
                    (void*)&Wout, (void*)&bout, (void*)&out, (void*)&ws};
    (void)hipLaunchCooperativeKernel((const void*)lstm_persist,
                                     dim3(NBLK), dim3(NTHR), args, 0, stream);
}

// Round 5
// 13591.550 us; speedup vs baseline: 7.8831x; 1.0169x over previous
//
#include <hip/hip_runtime.h>
#include <hip/hip_cooperative_groups.h>

namespace cg = cooperative_groups;

#define T_SEQ 4096
#define D_IN  512
#define D_H   2048
#define D_C   2560
#define D_OUT 512
#define NBLK  256
#define NTHR  1024
#define UPB   8     // hidden units per block (16 waves = 2 waves/unit)

__device__ __forceinline__ void dot4(float& acc, const float4& a, const float4& b) {
    acc = fmaf(a.x, b.x, acc);
    acc = fmaf(a.y, b.y, acc);
    acc = fmaf(a.z, b.z, acc);
    acc = fmaf(a.w, b.w, acc);
}

// ---- AGPR pinning: weights live in the accumulator file for the whole
// kernel. The allocator cannot rematerialize these (asm-defined) and has no
// pressure reason to spill them (gfx950 unified file, 60 AGPR + ~60 VGPR < 128).
#define AW(i, v) asm volatile("v_accvgpr_write_b32 %0, %1" : "=a"(aw[i]) : "v"(v))
#define AR(d, i) asm volatile("v_accvgpr_read_b32 %0, %1" : "=v"(d) : "a"(aw[i]))
#define DOT4A(acc, base, hv) do { float4 _w;                          \
        AR(_w.x, (base) + 0); AR(_w.y, (base) + 1);                   \
        AR(_w.z, (base) + 2); AR(_w.w, (base) + 3);                   \
        dot4(acc, _w, hv); } while (0)

// Cross-block h exchange: packed (tag<<32 | f32 bits), double-buffered by
// step parity. Only relaxed agent-scope atomics touch it (no acquire ->
// no L2 shootdowns). Data travels WITH the readiness tag: one L3 round trip.

__global__ __launch_bounds__(NTHR, 4) void lstm_persist(
    const float* __restrict__ x,         // [T_SEQ, D_IN]
    const float* __restrict__ hidden_in, // [D_H] (passthrough output)
    const float* __restrict__ Wi, const float* __restrict__ bi,
    const float* __restrict__ Wg, const float* __restrict__ bg,
    const float* __restrict__ Wo, const float* __restrict__ bo,
    const float* __restrict__ Wout, const float* __restrict__ bout,
    float* __restrict__ out,             // [D_OUT + D_H]
    unsigned long long* __restrict__ hb2)// d_ws: [2][D_H] tagged h
{
    cg::grid_group grid = cg::this_grid();
    const int tid  = threadIdx.x;
    const int lane = tid & 63;
    const int w    = tid >> 6;      // wave 0..15
    const int u    = w >> 1;        // unit-local 0..7
    const int hh   = w & 1;         // half: 0 -> comb[0,1280), 1 -> comb[1280,2560)
    const int j    = blockIdx.x * UPB + u;   // hidden unit 0..2047
    const int kb   = lane * 4;

    __shared__ float lds_h[D_H];
    __shared__ float part[16][3];

    // ---- init tagged-h buffers (ws poisoned 0xAA every call).
    // tag(buf0)=0 == h_0 = 0 valid; tag(buf1)=0 < 1 == not yet written.
    if (blockIdx.x == 0) {
        for (int i = tid; i < 2 * D_H; i += NTHR)
            __hip_atomic_store(&hb2[i], 0ull, __ATOMIC_RELAXED, __HIP_MEMORY_SCOPE_AGENT);
    }

    // ---- load + pin this wave's half-rows of Wi/Wg/Wo into 60 AGPRs
    float aw[60];
    {
        const size_t ro = (size_t)j * D_C + (size_t)hh * 1280 + kb;
#pragma unroll
        for (int r = 0; r < 5; ++r) {
            const float4 vi = *reinterpret_cast<const float4*>(Wi + ro + 256 * r);
            const float4 vg = *reinterpret_cast<const float4*>(Wg + ro + 256 * r);
            const float4 vo = *reinterpret_cast<const float4*>(Wo + ro + 256 * r);
            AW(r * 4 + 0, vi.x); AW(r * 4 + 1, vi.y);
            AW(r * 4 + 2, vi.z); AW(r * 4 + 3, vi.w);
            AW(20 + r * 4 + 0, vg.x); AW(20 + r * 4 + 1, vg.y);
            AW(20 + r * 4 + 2, vg.z); AW(20 + r * 4 + 3, vg.w);
            AW(40 + r * 4 + 0, vo.x); AW(40 + r * 4 + 1, vo.y);
            AW(40 + r * 4 + 2, vo.z); AW(40 + r * 4 + 3, vo.w);
        }
    }

    // biases for the 8 units, held by lanes 0..7 of wave 0
    float sbi = 0.f, sbg = 0.f, sbo = 0.f;
    if (tid < UPB) {
        sbi = bi[blockIdx.x * UPB + tid];
        sbg = bg[blockIdx.x * UPB + tid];
        sbo = bo[blockIdx.x * UPB + tid];
    }

    grid.sync();   // one-time: publishes init before anyone polls

    const int i0 = tid, i1 = tid + 1024;   // this thread's 2 polled units

#pragma unroll 1
    for (int t = 0; t < T_SEQ; ++t) {
        // x_t slice: issue before the poll so HBM latency hides under it
        float4 xv0, xv1;
        if (hh == 0) {
            const float* xt = x + (size_t)t * D_IN;
            xv0 = *reinterpret_cast<const float4*>(xt + kb);
            xv1 = *reinterpret_cast<const float4*>(xt + kb + 256);
        }

        // ---- poll tagged h (the poll IS the data read)
        const unsigned long long* hb = hb2 + (t & 1) * D_H;
        unsigned long long v0, v1;
        for (;;) {
            v0 = __hip_atomic_load(hb + i0, __ATOMIC_RELAXED, __HIP_MEMORY_SCOPE_AGENT);
            v1 = __hip_atomic_load(hb + i1, __ATOMIC_RELAXED, __HIP_MEMORY_SCOPE_AGENT);
            if ((unsigned)(v0 >> 32) >= (unsigned)t &&
                (unsigned)(v1 >> 32) >= (unsigned)t) break;
            __builtin_amdgcn_s_sleep(1);
        }
        lds_h[i0] = __uint_as_float((unsigned)v0);
        lds_h[i1] = __uint_as_float((unsigned)v1);
        __syncthreads();

        // ---- 3 gate dots over this wave's 1280-wide half (weights from AGPR)
        float ai = 0.f, ag = 0.f, ao = 0.f;
        if (hh == 0) {
            DOT4A(ai, 0, xv0);  DOT4A(ai, 4, xv1);
            DOT4A(ag, 20, xv0); DOT4A(ag, 24, xv1);
            DOT4A(ao, 40, xv0); DOT4A(ao, 44, xv1);
#pragma unroll
            for (int r = 2; r < 5; ++r) {
                const float4 hv = *reinterpret_cast<const float4*>(&lds_h[(r - 2) * 256 + kb]);
                DOT4A(ai, r * 4, hv);
                DOT4A(ag, 20 + r * 4, hv);
                DOT4A(ao, 40 + r * 4, hv);
            }
        } else {
#pragma unroll
            for (int r = 0; r < 5; ++r) {
                const float4 hv = *reinterpret_cast<const float4*>(&lds_h[768 + r * 256 + kb]);
                DOT4A(ai, r * 4, hv);
                DOT4A(ag, 20 + r * 4, hv);
                DOT4A(ao, 40 + r * 4, hv);
            }
        }

#pragma unroll
        for (int off = 32; off; off >>= 1) {
            ai += __shfl_xor(ai, off, 64);
            ag += __shfl_xor(ag, off, 64);
            ao += __shfl_xor(ao, off, 64);
        }
        if (lane == 0) { part[w][0] = ai; part[w][1] = ag; part[w][2] = ao; }
        __syncthreads();

        // ---- combine halves + activations + publish tagged h (lanes 0..7 of wave 0)
        if (tid < UPB) {
            const float zi = part[2 * tid][0] + part[2 * tid + 1][0] + sbi;
            const float zg = part[2 * tid][1] + part[2 * tid + 1][1] + sbg;
            const float zo = part[2 * tid][2] + part[2 * tid + 1][2] + sbo;
            const float it = 1.0f / (1.0f + __expf(-zi));
            const float e2g = __expf(-2.0f * zg);
            const float gt = (1.0f - e2g) / (1.0f + e2g);
            const float ot = 1.0f / (1.0f + __expf(-zo));
            const float c  = it * gt;
            const float e2c = __expf(-2.0f * c);
            const float th = (1.0f - e2c) / (1.0f + e2c);
            const unsigned long long pk =
                ((unsigned long long)(unsigned)(t + 1) << 32) |
                (unsigned long long)__float_as_uint(ot * th);
            __hip_atomic_store(&hb2[((t + 1) & 1) * D_H + blockIdx.x * UPB + tid],
                               pk, __ATOMIC_RELAXED, __HIP_MEMORY_SCOPE_AGENT);
        }
        // no extra barrier: next iteration's poll gates everything
    }

    // ---- epilogue: out = Wout @ h_final + bout ; passthrough hidden_in
    if (blockIdx.x < 64) {
        // final h has tag T_SEQ in buffer 0 (T_SEQ even)
        unsigned long long v0, v1;
        for (;;) {
            v0 = __hip_atomic_load(hb2 + i0, __ATOMIC_RELAXED, __HIP_MEMORY_SCOPE_AGENT);
            v1 = __hip_atomic_load(hb2 + i1, __ATOMIC_RELAXED, __HIP_MEMORY_SCOPE_AGENT);
            if ((unsigned)(v0 >> 32) >= (unsigned)T_SEQ &&
                (unsigned)(v1 >> 32) >= (unsigned)T_SEQ) break;
            __builtin_amdgcn_s_sleep(1);
        }
        lds_h[i0] = __uint_as_float((unsigned)v0);
        lds_h[i1] = __uint_as_float((unsigned)v1);
        __syncthreads();

        if (w < 8) {
            const int ow = blockIdx.x * 8 + w;
            const float* pw = Wout + (size_t)ow * D_H + kb;
            float acc = 0.f;
#pragma unroll
            for (int r = 0; r < 8; ++r) {
                const float4 w4 = *reinterpret_cast<const float4*>(pw + 256 * r);
                const float4 hv = *reinterpret_cast<const float4*>(&lds_h[kb + 256 * r]);
                dot4(acc, w4, hv);
            }
#pragma unroll
            for (int off = 32; off; off >>= 1) acc += __shfl_xor(acc, off, 64);
            if (lane == 0) out[ow] = acc + bout[ow];
        }
    } else if (blockIdx.x >= 64 && blockIdx.x < 66) {
        const int idx = (blockIdx.x - 64) * NTHR + tid;   // 2048 floats
        out[D_OUT + idx] = hidden_in[idx];
    }
}

extern "C" void kernel_launch(void* const* d_in, const int* in_sizes, int n_in,
                              void* d_out, int out_size, void* d_ws, size_t ws_size,
                              hipStream_t stream) {
    const float* x      = (const float*)d_in[0];
    const float* hidden = (const float*)d_in[1];
    const float* Wi     = (const float*)d_in[2];
    const float* bi     = (const float*)d_in[3];
    const float* Wg     = (const float*)d_in[4];
    const float* bg     = (const float*)d_in[5];
    const float* Wo     = (const float*)d_in[6];
    const float* bo     = (const float*)d_in[7];
    const float* Wout   = (const float*)d_in[8];
    const float* bout   = (const float*)d_in[9];
    float* out = (float*)d_out;
    unsigned long long* hb2 = (unsigned long long*)d_ws;  // 2*2048*8 = 32 KB

    void* args[] = {(void*)&x, (void*)&hidden, (void*)&Wi, (void*)&bi,
                    (void*)&Wg, (void*)&bg, (void*)&Wo, (void*)&bo,
                    (void*)&Wout, (void*)&bout, (void*)&out, (void*)&hb2};
    (void)hipLaunchCooperativeKernel((const void*)lstm_persist,
                                     dim3(NBLK), dim3(NTHR), args, 0, stream);
}